// Round 2
// baseline (497.910 us; speedup 1.0000x reference)
//
#include <hip/hip_runtime.h>
#include <hip/hip_bf16.h>

#define NTOK 49
#define CDIM 128
#define C3   384
#define NHEAD 4
#define HDIM 32
#define SCALE 0.17677669529663687f
#define LOG2E 1.4426950408889634f
#define SC2   (0.17677669529663687f * 1.4426950408889634f)
#define TSV 52   // vT token stride (52*2=104 B rows, 8B-aligned for b64)

typedef __attribute__((ext_vector_type(8))) __bf16 bf16x8;
typedef __attribute__((ext_vector_type(4))) __bf16 bf16x4;
typedef __attribute__((ext_vector_type(4))) float f32x4;

#define PIN(v) asm volatile("" : "+v"(v))

// XOR swizzle for 256B-stride row-major LDS tiles: byte ^= (row&7)<<4
__device__ __forceinline__ int swz(int b) { return b ^ ((b >> 4) & 0x70); }

__device__ __forceinline__ f32x4 mfma32(bf16x8 a, bf16x8 b, f32x4 c) {
  return __builtin_amdgcn_mfma_f32_16x16x32_bf16(a, b, c, 0, 0, 0);
}
// 16x16x16 semantics emulated on 16x16x32: real kk at k' = (kk>>2)*8 + (kk&3)
// (lane-group lg holds j=0..3), upper j=4..7 dead: one operand zero-padded,
// the other merely needs defined-finite data there (dup).
__device__ __forceinline__ bf16x8 dup8(bf16x4 t) {
  uint2 w = __builtin_bit_cast(uint2, t);
  uint4 r; r.x = w.x; r.y = w.y; r.z = w.x; r.w = w.y;
  return __builtin_bit_cast(bf16x8, r);
}
__device__ __forceinline__ bf16x8 zpad8(bf16x4 t) {
  uint2 w = __builtin_bit_cast(uint2, t);
  uint4 r; r.x = w.x; r.y = w.y; r.z = 0u; r.w = 0u;
  return __builtin_bit_cast(bf16x8, r);
}
__device__ __forceinline__ unsigned pkbf(float lo, float hi) {
  unsigned short a = __builtin_bit_cast(unsigned short, (__bf16)lo);
  unsigned short b = __builtin_bit_cast(unsigned short, (__bf16)hi);
  return ((unsigned)b << 16) | (unsigned)a;
}

// ws layout (bytes):
//   qkvT  __bf16[384][128] @ 0       qkvT[n][k] = qkv_w[k][n]; q rows pre-scaled by SCALE*LOG2E
//   projT __bf16[128][128] @ 98304
//   blut  float [4][64][64]@ 131072  rel-bias LUT [h][q][k] * LOG2E, k>=49 -> -1.44e30

__global__ __launch_bounds__(256) void prep_kernel(
    const float* __restrict__ qkv_w, const float* __restrict__ proj_w,
    const float* __restrict__ bias_table,
    __bf16* __restrict__ qkvT, __bf16* __restrict__ projT, float* __restrict__ blut)
{
  int o = blockIdx.x * 256 + threadIdx.x;
  if (o < CDIM * C3) {
    int k = o / C3, n = o - k * C3;
    float v = qkv_w[o];
    if (n < CDIM) v *= SC2;                // fold softmax scale AND log2e into q weights
    qkvT[n * CDIM + k] = (__bf16)v;
  } else if (o < CDIM * C3 + CDIM * CDIM) {
    int o2 = o - CDIM * C3;
    int k = o2 >> 7, n = o2 & 127;
    projT[n * CDIM + k] = (__bf16)proj_w[o2];
  } else if (o < CDIM * C3 + CDIM * CDIM + NHEAD * 64 * 64) {
    int t3 = o - (CDIM * C3 + CDIM * CDIM);
    int hh = t3 >> 12, r = (t3 >> 6) & 63, c = t3 & 63;
    float v;
    if (c >= NTOK) v = -1e30f;             // softmax mask for padded key columns
    else if (r >= NTOK) v = 0.0f;          // padded query rows: finite, never stored
    else {
      int idx = (r / 7 - c / 7 + 6) * 13 + (r % 7 - c % 7 + 6);
      v = bias_table[idx * NHEAD + hh];
    }
    blut[t3] = v * LOG2E;                  // fold log2e -> exp2 in kernel
  }
}

// 512 threads = 8 waves. LDS 38400 B + VGPR<=64 -> 4 blocks/CU (32 waves/CU).
// 3 barriers. q and P never touch LDS.
__global__ __launch_bounds__(512, 8) void attn_kernel(
    const float* __restrict__ x, const float* __restrict__ qkv_b,
    const float* __restrict__ proj_b, const char* __restrict__ ws,
    float* __restrict__ out)
{
  __shared__ __align__(16) char smem[38400];
  char*   xo_ = smem;                      // [49][128] bf16, swz: x tile, then O tile
  char*   ks_ = smem + 12544;              // [49][128] bf16, swz: K[tok][ch]
  __bf16* vT_ = (__bf16*)(smem + 25088);   // [128][52]  bf16: V^T[ch][tok], cols 49..51 zeroed

  const __bf16* qkvT  = (const __bf16*)ws;
  const __bf16* projT = (const __bf16*)(ws + 98304);
  const float*  blut  = (const float*)(ws + 131072);

  const int tid  = threadIdx.x;
  const int wave = tid >> 6;
  const int lane = tid & 63;
  const int l15  = lane & 15;
  const int lg   = lane >> 4;
  const int h    = wave & 3, half = wave >> 2;
  const int hc   = h * HDIM;               // head channel base
  const int chw  = wave * 16;              // k/v/proj channel base for this wave

  const int win = blockIdx.x;
  const int b  = win >> 6;
  const int wh = (win >> 3) & 7;
  const int ww = win & 7;
  const float* xbase = x + (((b * 56) + wh * 7) * 56 + ww * 7) * CDIM;

  // ---- phase 0: stage x rows 0..48 into LDS (bf16, swizzled) ----
  {
    int L = tid;
    #pragma unroll
    for (int p = 0; p < 2; ++p) {
      if (L < 784) {                        // 49 rows * 16 chunks
        int r = L >> 4, c = L & 15;
        const float* g = xbase + ((r / 7) * 56 + (r % 7)) * CDIM + c * 8;
        f32x4 x0 = *(const f32x4*)g;
        f32x4 x1 = *(const f32x4*)(g + 4);
        bf16x8 v8;
        v8[0] = (__bf16)x0[0]; v8[1] = (__bf16)x0[1]; v8[2] = (__bf16)x0[2]; v8[3] = (__bf16)x0[3];
        v8[4] = (__bf16)x1[0]; v8[5] = (__bf16)x1[1]; v8[6] = (__bf16)x1[2]; v8[7] = (__bf16)x1[3];
        *(bf16x8*)(xo_ + swz(r * 256 + c * 16)) = v8;
      }
      L += 512;
    }
  }

  // ---- prefetch k/v weight A-fragments (transposed GEMM: A = W^T rows = channels) ----
  bf16x8 awk[4], awv[4];
  #pragma unroll
  for (int kt = 0; kt < 4; ++kt) {
    awk[kt] = *(const bf16x8*)(qkvT + (CDIM + chw + l15) * CDIM + kt * 32 + lg * 8);     PIN(awk[kt]);
    awv[kt] = *(const bf16x8*)(qkvT + (2 * CDIM + chw + l15) * CDIM + kt * 32 + lg * 8); PIN(awv[kt]);
  }
  f32x4 kbv = *(const f32x4*)(qkv_b + CDIM + chw + lg * 4);
  f32x4 vbv = *(const f32x4*)(qkv_b + 2 * CDIM + chw + lg * 4);

  __syncthreads();   // [1] x tile ready

  // ---- pass k: K^T = Wk^T * X^T; C rows=ch, cols=tok -> vector b64 stores ----
  #pragma unroll
  for (int mt = 0; mt < 4; ++mt) {
    int tok = mt * 16 + l15;
    int r = tok > 48 ? 48 : tok;
    bf16x8 a[4];
    #pragma unroll
    for (int kt = 0; kt < 4; ++kt)
      a[kt] = *(const bf16x8*)(xo_ + swz(r * 256 + kt * 64 + lg * 16));
    f32x4 ck; ck[0]=0.f; ck[1]=0.f; ck[2]=0.f; ck[3]=0.f;
    #pragma unroll
    for (int kt = 0; kt < 4; ++kt) ck = mfma32(awk[kt], a[kt], ck);
    if (tok <= 48) {
      bf16x4 k4;
      #pragma unroll
      for (int i = 0; i < 4; ++i) k4[i] = (__bf16)(ck[i] + kbv[i]);
      *(bf16x4*)(ks_ + swz(tok * 256 + (chw + lg * 4) * 2)) = k4;
    }
  }

  // ---- pass v: V^T stored [ch][tok]; zero-fill tok 49..51 (read-reach of clamped PV loads) ----
  #pragma unroll
  for (int mt = 0; mt < 4; ++mt) {
    int tok = mt * 16 + l15;
    int r = tok > 48 ? 48 : tok;
    bf16x8 a[4];
    #pragma unroll
    for (int kt = 0; kt < 4; ++kt)
      a[kt] = *(const bf16x8*)(xo_ + swz(r * 256 + kt * 64 + lg * 16));
    f32x4 cv; cv[0]=0.f; cv[1]=0.f; cv[2]=0.f; cv[3]=0.f;
    #pragma unroll
    for (int kt = 0; kt < 4; ++kt) cv = mfma32(awv[kt], a[kt], cv);
    if (tok <= 48) {
      #pragma unroll
      for (int i = 0; i < 4; ++i)
        vT_[(chw + lg * 4 + i) * TSV + tok] = (__bf16)(cv[i] + vbv[i]);
    } else if (tok <= 51) {
      #pragma unroll
      for (int i = 0; i < 4; ++i)
        vT_[(chw + lg * 4 + i) * TSV + tok] = (__bf16)0.0f;
    }
  }

  // ---- pass q: Q^T for this wave's own head+half, kept in registers (packed bf16 pairs) ----
  unsigned pkq[2][2][2];                   // [mi][ct][t]: Q^T[ch=hc+ct*16+lg*4+2t{,+1}][q=m0+l15]
  #pragma unroll
  for (int ct = 0; ct < 2; ++ct) {
    bf16x8 awq[4];
    #pragma unroll
    for (int kt = 0; kt < 4; ++kt)
      awq[kt] = *(const bf16x8*)(qkvT + (hc + ct * 16 + l15) * CDIM + kt * 32 + lg * 8);
    f32x4 qbv = *(const f32x4*)(qkv_b + hc + ct * 16 + lg * 4);
    #pragma unroll
    for (int mi = 0; mi < 2; ++mi) {
      int tok = (2 * half + mi) * 16 + l15;
      int r = tok > 48 ? 48 : tok;
      bf16x8 a[4];
      #pragma unroll
      for (int kt = 0; kt < 4; ++kt)
        a[kt] = *(const bf16x8*)(xo_ + swz(r * 256 + kt * 64 + lg * 16));
      f32x4 qc; qc[0]=0.f; qc[1]=0.f; qc[2]=0.f; qc[3]=0.f;
      #pragma unroll
      for (int kt = 0; kt < 4; ++kt) qc = mfma32(awq[kt], a[kt], qc);
      pkq[mi][ct][0] = pkbf(qc[0] + qbv[0] * SC2, qc[1] + qbv[1] * SC2);
      pkq[mi][ct][1] = pkbf(qc[2] + qbv[2] * SC2, qc[3] + qbv[3] * SC2);
    }
  }

  __syncthreads();   // [2] K/V staged; all x reads done (O may overlay xo_)

  // ---- phase 2: attention, fully register-resident softmax ----
  const float* blh = blut + h * 4096;
  bf16x8 akf[4];                           // K A-frags (x32): rows=tok(16/tile), k=32 head ch
  #pragma unroll
  for (int nt = 0; nt < 4; ++nt) {
    int rr = nt * 16 + l15; if (rr > 48) rr = 48;
    akf[nt] = *(const bf16x8*)(ks_ + swz(rr * 256 + (hc + lg * 8) * 2));
  }

  #pragma unroll
  for (int mi = 0; mi < 2; ++mi) {
    const int m0 = (2 * half + mi) * 16;

    // assemble Q^T B-frag (x32) from in-register pkq via 8 bpermute + 4 select
    unsigned bqw[4];
    #pragma unroll
    for (int d = 0; d < 4; ++d) {
      int srcl = ((lg & 1) * 2 + (d >> 1)) * 16 + l15;
      unsigned w0 = __shfl(pkq[mi][0][d & 1], srcl);
      unsigned w1 = __shfl(pkq[mi][1][d & 1], srcl);
      bqw[d] = (lane >= 32) ? w1 : w0;
    }
    uint4 bqv; bqv.x = bqw[0]; bqv.y = bqw[1]; bqv.z = bqw[2]; bqv.w = bqw[3];
    bf16x8 bq8 = __builtin_bit_cast(bf16x8, bqv);

    float psum = 0.f;
    bf16x4 pa4[4];                         // P^T fragments, in-lane
    #pragma unroll
    for (int nt = 0; nt < 4; ++nt) {
      f32x4 bias = *(const f32x4*)(blh + (m0 + l15) * 64 + nt * 16 + lg * 4);
      f32x4 z; z[0]=0.f; z[1]=0.f; z[2]=0.f; z[3]=0.f;
      f32x4 s = mfma32(akf[nt], bq8, z);   // S^T[tok=nt*16+lg*4+i][q=m0+l15]
      float e0 = exp2f(s[0] + bias[0]);
      float e1 = exp2f(s[1] + bias[1]);
      float e2 = exp2f(s[2] + bias[2]);
      float e3 = exp2f(s[3] + bias[3]);
      psum += (e0 + e1) + (e2 + e3);
      uint2 pw; pw.x = pkbf(e0, e1); pw.y = pkbf(e2, e3);
      pa4[nt] = __builtin_bit_cast(bf16x4, pw);
    }
    psum += __shfl_xor(psum, 16);          // reduce over lg groups (same q col)
    psum += __shfl_xor(psum, 32);
    const float inv = __builtin_amdgcn_rcpf(psum);

    // PV as O^T = V^T * P^T, K=16 emulated on x32 (pa zero-padded, V dup-padded)
    f32x4 ot0, ot1;
    ot0[0]=0.f; ot0[1]=0.f; ot0[2]=0.f; ot0[3]=0.f;
    ot1[0]=0.f; ot1[1]=0.f; ot1[2]=0.f; ot1[3]=0.f;
    #pragma unroll
    for (int nt = 0; nt < 4; ++nt) {
      int tb = nt * 16 + lg * 4; if (tb > 48) tb = 48;
      bf16x8 pb8 = zpad8(pa4[nt]);
      bf16x4 v0 = *(const bf16x4*)(vT_ + (hc + l15) * TSV + tb);
      bf16x4 v1 = *(const bf16x4*)(vT_ + (hc + 16 + l15) * TSV + tb);
      ot0 = mfma32(dup8(v0), pb8, ot0);
      ot1 = mfma32(dup8(v1), pb8, ot1);
    }
    const int rq = m0 + l15;
    if (rq <= 48) {
      #pragma unroll
      for (int i = 0; i < 4; ++i) {
        *(__bf16*)(xo_ + swz(rq * 256 + (hc + lg * 4 + i) * 2))      = (__bf16)(ot0[i] * inv);
        *(__bf16*)(xo_ + swz(rq * 256 + (hc + 16 + lg * 4 + i) * 2)) = (__bf16)(ot1[i] * inv);
      }
    }
  }

  // ---- prefetch proj weights: latency hides under barrier ----
  bf16x8 bp[4];
  #pragma unroll
  for (int kt = 0; kt < 4; ++kt) {
    bp[kt] = *(const bf16x8*)(projT + (chw + l15) * CDIM + kt * 32 + lg * 8);
    PIN(bp[kt]);
  }
  const float pb = proj_b[chw + l15];

  __syncthreads();   // [3] O ready across waves

  // ---- phase 3: proj GEMM, wave owns 16 output cols ----
  float* outw = out + (((b * 56) + wh * 7) * 56 + ww * 7) * CDIM;
  #pragma unroll
  for (int mt = 0; mt < 4; ++mt) {
    int rr = mt * 16 + l15; int rc = rr > 48 ? 48 : rr;
    bf16x8 ao[4];
    #pragma unroll
    for (int kt = 0; kt < 4; ++kt)
      ao[kt] = *(const bf16x8*)(xo_ + swz(rc * 256 + kt * 64 + lg * 16));
    f32x4 c0; c0[0]=0.f; c0[1]=0.f; c0[2]=0.f; c0[3]=0.f;
    #pragma unroll
    for (int kt = 0; kt < 4; ++kt) c0 = mfma32(ao[kt], bp[kt], c0);
    #pragma unroll
    for (int i = 0; i < 4; ++i) {
      const int r = mt * 16 + lg * 4 + i;
      if (r < NTOK) {
        float* po = outw + ((r / 7) * 56 + (r % 7)) * CDIM + chw;
        po[l15] = c0[i] + pb;
      }
    }
  }
}

extern "C" void kernel_launch(void* const* d_in, const int* in_sizes, int n_in,
                              void* d_out, int out_size, void* d_ws, size_t ws_size,
                              hipStream_t stream) {
  const float* x          = (const float*)d_in[0];
  const float* qkv_w      = (const float*)d_in[1];
  const float* qkv_b      = (const float*)d_in[2];
  const float* proj_w     = (const float*)d_in[3];
  const float* proj_b     = (const float*)d_in[4];
  const float* bias_table = (const float*)d_in[5];

  __bf16* qkvT  = (__bf16*)d_ws;
  __bf16* projT = qkvT + C3 * CDIM;
  float*  blut  = (float*)((char*)d_ws + 131072);
  float*  out   = (float*)d_out;

  hipLaunchKernelGGL(prep_kernel, dim3(320), dim3(256), 0, stream,
                     qkv_w, proj_w, bias_table, qkvT, projT, blut);
  hipLaunchKernelGGL(attn_kernel, dim3(4096), dim3(512), 0, stream,
                     x, qkv_b, proj_b, (const char*)d_ws, out);
}

// Round 3
// 328.287 us; speedup vs baseline: 1.5167x; 1.5167x over previous
//
#include <hip/hip_runtime.h>
#include <hip/hip_bf16.h>

#define NTOK 49
#define CDIM 128
#define C3   384
#define NHEAD 4
#define HDIM 32
#define SCALE 0.17677669529663687f
#define LOG2E 1.4426950408889634f
#define SC2   (0.17677669529663687f * 1.4426950408889634f)
#define QS2 132   // x/o and k row stride, elems (264 B: 66 words == 2 banks/row -> even b128 spread)
#define TSV 52    // vT token stride (104 B rows, 8B-aligned)

typedef __attribute__((ext_vector_type(8))) __bf16 bf16x8;
typedef __attribute__((ext_vector_type(4))) __bf16 bf16x4;
typedef __attribute__((ext_vector_type(4))) float f32x4;

#define PIN(v) asm volatile("" : "+v"(v))

__device__ __forceinline__ f32x4 mfma32(bf16x8 a, bf16x8 b, f32x4 c) {
  return __builtin_amdgcn_mfma_f32_16x16x32_bf16(a, b, c, 0, 0, 0);
}
// K=16 semantics emulated on x32: j=0..3 real, j=4..7 dead (one operand zero-padded,
// the other dup'd so the dead half is defined-finite).
__device__ __forceinline__ bf16x8 dup8(bf16x4 t) {
  uint2 w = __builtin_bit_cast(uint2, t);
  uint4 r; r.x = w.x; r.y = w.y; r.z = w.x; r.w = w.y;
  return __builtin_bit_cast(bf16x8, r);
}
__device__ __forceinline__ bf16x8 zpad8(bf16x4 t) {
  uint2 w = __builtin_bit_cast(uint2, t);
  uint4 r; r.x = w.x; r.y = w.y; r.z = 0u; r.w = 0u;
  return __builtin_bit_cast(bf16x8, r);
}
__device__ __forceinline__ unsigned pkbf(float lo, float hi) {
  unsigned short a = __builtin_bit_cast(unsigned short, (__bf16)lo);
  unsigned short b = __builtin_bit_cast(unsigned short, (__bf16)hi);
  return ((unsigned)b << 16) | (unsigned)a;
}

// ws layout (bytes):
//   qkvT  __bf16[384][128] @ 0       qkvT[n][k] = qkv_w[k][n]; q rows pre-scaled by SCALE*LOG2E
//   projT __bf16[128][128] @ 98304
//   blut  float [4][64][64]@ 131072  rel-bias LUT [h][q][k] * LOG2E, k>=49 -> -1.44e30

__global__ __launch_bounds__(256) void prep_kernel(
    const float* __restrict__ qkv_w, const float* __restrict__ proj_w,
    const float* __restrict__ bias_table,
    __bf16* __restrict__ qkvT, __bf16* __restrict__ projT, float* __restrict__ blut)
{
  int o = blockIdx.x * 256 + threadIdx.x;
  if (o < CDIM * C3) {
    int k = o / C3, n = o - k * C3;
    float v = qkv_w[o];
    if (n < CDIM) v *= SC2;                // fold softmax scale AND log2e into q weights
    qkvT[n * CDIM + k] = (__bf16)v;
  } else if (o < CDIM * C3 + CDIM * CDIM) {
    int o2 = o - CDIM * C3;
    int k = o2 >> 7, n = o2 & 127;
    projT[n * CDIM + k] = (__bf16)proj_w[o2];
  } else if (o < CDIM * C3 + CDIM * CDIM + NHEAD * 64 * 64) {
    int t3 = o - (CDIM * C3 + CDIM * CDIM);
    int hh = t3 >> 12, r = (t3 >> 6) & 63, c = t3 & 63;
    float v;
    if (c >= NTOK) v = -1e30f;             // softmax mask for padded key columns
    else if (r >= NTOK) v = 0.0f;          // padded query rows: finite, never stored
    else {
      int idx = (r / 7 - c / 7 + 6) * 13 + (r % 7 - c % 7 + 6);
      v = bias_table[idx * NHEAD + hh];
    }
    blut[t3] = v * LOG2E;                  // fold log2e -> exp2 in kernel
  }
}

// 512 threads = 8 waves. LDS 39184 B. launch_bounds(512,6): cap ~85 VGPR, no spill;
// if compiler lands <=64 VGPR the LDS budget allows 4 blocks/CU.
// 3 barriers. q and P never touch LDS.
__global__ __launch_bounds__(512, 6) void attn_kernel(
    const float* __restrict__ x, const float* __restrict__ qkv_b,
    const float* __restrict__ proj_b, const char* __restrict__ ws,
    float* __restrict__ out)
{
  __shared__ __align__(16) char smem[39184];
  char*   xo_ = smem;                      // [49][132] bf16: x tile, later O tile
  char*   ks_ = smem + 12936;              // [49][132] bf16: K[tok][ch]
  __bf16* vT_ = (__bf16*)(smem + 25872);   // [128][52]  bf16: V^T[ch][tok], cols 49..51 zeroed

  const __bf16* qkvT  = (const __bf16*)ws;
  const __bf16* projT = (const __bf16*)(ws + 98304);
  const float*  blut  = (const float*)(ws + 131072);

  const int tid  = threadIdx.x;
  const int wave = tid >> 6;
  const int lane = tid & 63;
  const int l15  = lane & 15;
  const int lg   = lane >> 4;
  const int h    = wave & 3, mhalf = wave >> 2;
  const int hc   = h * HDIM;               // head channel base
  const int chw  = wave * 16;              // k/v/proj channel base for this wave

  const int win = blockIdx.x;
  const int b  = win >> 6;
  const int wh = (win >> 3) & 7;
  const int ww = win & 7;
  const float* xbase = x + (((b * 56) + wh * 7) * 56 + ww * 7) * CDIM;

  // per-lane clamped row byte-bases for the 132-stride tiles; reused by every phase
  int rb[4];
  #pragma unroll
  for (int mt = 0; mt < 4; ++mt) {
    int t = mt * 16 + l15; if (t > 48) t = 48;
    rb[mt] = t * (QS2 * 2);
  }

  // ---- phase 0: stage x rows 0..48 into LDS bf16 [49][132] ----
  {
    int L = tid;
    #pragma unroll
    for (int p = 0; p < 2; ++p) {
      if (L < 784) {                        // 49 rows * 16 chunks
        int r = L >> 4, c = L & 15;
        const float* g = xbase + ((r / 7) * 56 + (r % 7)) * CDIM + c * 8;
        f32x4 x0 = *(const f32x4*)g;
        f32x4 x1 = *(const f32x4*)(g + 4);
        bf16x8 v8;
        v8[0] = (__bf16)x0[0]; v8[1] = (__bf16)x0[1]; v8[2] = (__bf16)x0[2]; v8[3] = (__bf16)x0[3];
        v8[4] = (__bf16)x1[0]; v8[5] = (__bf16)x1[1]; v8[6] = (__bf16)x1[2]; v8[7] = (__bf16)x1[3];
        *(bf16x8*)(xo_ + r * (QS2 * 2) + c * 16) = v8;
      }
      L += 512;
    }
  }

  // ---- prefetch k/v weight A-fragments (transposed GEMM: A rows = channels) ----
  bf16x8 awk[4], awv[4];
  #pragma unroll
  for (int kt = 0; kt < 4; ++kt) {
    awk[kt] = *(const bf16x8*)(qkvT + (CDIM + chw + l15) * CDIM + kt * 32 + lg * 8);
    awv[kt] = *(const bf16x8*)(qkvT + (2 * CDIM + chw + l15) * CDIM + kt * 32 + lg * 8);
  }
  f32x4 kbv = *(const f32x4*)(qkv_b + CDIM + chw + lg * 4);
  f32x4 vbv = *(const f32x4*)(qkv_b + 2 * CDIM + chw + lg * 4);

  __syncthreads();   // [1] x tile ready

  // ---- pass k/v: C rows = channels, cols = tokens ----
  #pragma unroll
  for (int mt = 0; mt < 4; ++mt) {
    const int tok = mt * 16 + l15;
    bf16x8 a[4];
    #pragma unroll
    for (int kt = 0; kt < 4; ++kt)
      a[kt] = *(const bf16x8*)(xo_ + rb[mt] + kt * 64 + lg * 16);
    f32x4 ck, cv;
    ck[0]=0.f; ck[1]=0.f; ck[2]=0.f; ck[3]=0.f;
    cv[0]=0.f; cv[1]=0.f; cv[2]=0.f; cv[3]=0.f;
    #pragma unroll
    for (int kt = 0; kt < 4; ++kt) {
      ck = mfma32(awk[kt], a[kt], ck);
      cv = mfma32(awv[kt], a[kt], cv);
    }
    if (tok <= 48) {
      bf16x4 k4;
      #pragma unroll
      for (int i = 0; i < 4; ++i) k4[i] = (__bf16)(ck[i] + kbv[i]);
      *(bf16x4*)(ks_ + tok * (QS2 * 2) + (chw + lg * 4) * 2) = k4;   // K[tok][ch], b64
      #pragma unroll
      for (int i = 0; i < 4; ++i)
        vT_[(chw + lg * 4 + i) * TSV + tok] = (__bf16)(cv[i] + vbv[i]);
    } else if (tok <= 51) {                 // zero-fill vT cols 49..51 (clamped PV load reach)
      #pragma unroll
      for (int i = 0; i < 4; ++i)
        vT_[(chw + lg * 4 + i) * TSV + tok] = (__bf16)0.0f;
    }
  }

  // ---- pass q: this wave's own head+half, kept in registers (packed bf16 pairs) ----
  int rbq[2];
  rbq[0] = mhalf ? rb[2] : rb[0];
  rbq[1] = mhalf ? rb[3] : rb[1];
  unsigned pkq[2][2][2];                   // [mi][ct][t]: Q^T[ch=hc+ct*16+lg*4+2t{,+1}][q]
  #pragma unroll
  for (int ct = 0; ct < 2; ++ct) {
    bf16x8 awq[4];
    #pragma unroll
    for (int kt = 0; kt < 4; ++kt)
      awq[kt] = *(const bf16x8*)(qkvT + (hc + ct * 16 + l15) * CDIM + kt * 32 + lg * 8);
    f32x4 qbv = *(const f32x4*)(qkv_b + hc + ct * 16 + lg * 4);
    #pragma unroll
    for (int mi = 0; mi < 2; ++mi) {
      bf16x8 a[4];
      #pragma unroll
      for (int kt = 0; kt < 4; ++kt)
        a[kt] = *(const bf16x8*)(xo_ + rbq[mi] + kt * 64 + lg * 16);
      f32x4 qc; qc[0]=0.f; qc[1]=0.f; qc[2]=0.f; qc[3]=0.f;
      #pragma unroll
      for (int kt = 0; kt < 4; ++kt) qc = mfma32(awq[kt], a[kt], qc);
      pkq[mi][ct][0] = pkbf(qc[0] + qbv[0] * SC2, qc[1] + qbv[1] * SC2);
      pkq[mi][ct][1] = pkbf(qc[2] + qbv[2] * SC2, qc[3] + qbv[3] * SC2);
    }
  }

  __syncthreads();   // [2] K/V staged; all x reads done (O may overlay xo_)

  // ---- phase 2: attention, register-resident softmax ----
  const float* blh = blut + h * 4096;
  bf16x8 akf[4];                           // K A-frags: rows = tokens, k = 32 head channels
  #pragma unroll
  for (int nt = 0; nt < 4; ++nt)
    akf[nt] = *(const bf16x8*)(ks_ + rb[nt] + (hc + lg * 8) * 2);

  #pragma unroll
  for (int mi = 0; mi < 2; ++mi) {
    const int m0 = (2 * mhalf + mi) * 16;

    // assemble Q^T B-frag from in-register pkq via 8 bpermute + 4 select
    unsigned bqw[4];
    #pragma unroll
    for (int d = 0; d < 4; ++d) {
      int srcl = ((lg & 1) * 2 + (d >> 1)) * 16 + l15;
      unsigned w0 = __shfl(pkq[mi][0][d & 1], srcl);
      unsigned w1 = __shfl(pkq[mi][1][d & 1], srcl);
      bqw[d] = (lane >= 32) ? w1 : w0;
    }
    uint4 bqv; bqv.x = bqw[0]; bqv.y = bqw[1]; bqv.z = bqw[2]; bqv.w = bqw[3];
    bf16x8 bq8 = __builtin_bit_cast(bf16x8, bqv);

    float psum = 0.f;
    bf16x4 pa4[4];                         // P^T fragments, in-lane
    #pragma unroll
    for (int nt = 0; nt < 4; ++nt) {
      f32x4 bias = *(const f32x4*)(blh + (m0 + l15) * 64 + nt * 16 + lg * 4);
      f32x4 z; z[0]=0.f; z[1]=0.f; z[2]=0.f; z[3]=0.f;
      f32x4 s = mfma32(akf[nt], bq8, z);   // S^T[tok=nt*16+lg*4+i][q=m0+l15]
      float e0 = exp2f(s[0] + bias[0]);
      float e1 = exp2f(s[1] + bias[1]);
      float e2 = exp2f(s[2] + bias[2]);
      float e3 = exp2f(s[3] + bias[3]);
      psum += (e0 + e1) + (e2 + e3);
      uint2 pw; pw.x = pkbf(e0, e1); pw.y = pkbf(e2, e3);
      pa4[nt] = __builtin_bit_cast(bf16x4, pw);
    }
    psum += __shfl_xor(psum, 16);          // reduce over lg groups (same q column)
    psum += __shfl_xor(psum, 32);
    const float inv = __builtin_amdgcn_rcpf(psum);

    // PV as O^T = V^T * P^T, K=16 emulated (pa zero-padded, V dup-padded)
    f32x4 ot0, ot1;
    ot0[0]=0.f; ot0[1]=0.f; ot0[2]=0.f; ot0[3]=0.f;
    ot1[0]=0.f; ot1[1]=0.f; ot1[2]=0.f; ot1[3]=0.f;
    const __bf16* vrow0 = vT_ + (hc + l15) * TSV;
    const __bf16* vrow1 = vrow0 + 16 * TSV;
    #pragma unroll
    for (int nt = 0; nt < 4; ++nt) {
      int tb = nt * 16 + lg * 4; if (tb > 48) tb = 48;
      bf16x8 pb8 = zpad8(pa4[nt]);
      bf16x4 v0 = *(const bf16x4*)(vrow0 + tb);
      bf16x4 v1 = *(const bf16x4*)(vrow1 + tb);
      ot0 = mfma32(dup8(v0), pb8, ot0);
      ot1 = mfma32(dup8(v1), pb8, ot1);
    }
    const int rq = m0 + l15;
    if (rq <= 48) {
      char* orow = xo_ + rq * (QS2 * 2);
      #pragma unroll
      for (int i = 0; i < 4; ++i) {
        *(__bf16*)(orow + (hc + lg * 4 + i) * 2)      = (__bf16)(ot0[i] * inv);
        *(__bf16*)(orow + (hc + 16 + lg * 4 + i) * 2) = (__bf16)(ot1[i] * inv);
      }
    }
  }

  // ---- prefetch proj weights: latency hides under barrier ----
  bf16x8 bp[4];
  #pragma unroll
  for (int kt = 0; kt < 4; ++kt) {
    bp[kt] = *(const bf16x8*)(projT + (chw + l15) * CDIM + kt * 32 + lg * 8);
    PIN(bp[kt]);
  }
  const float pb = proj_b[chw + l15];

  __syncthreads();   // [3] O ready across waves

  // ---- phase 3: proj GEMM, wave owns 16 output cols ----
  float* outw = out + (((b * 56) + wh * 7) * 56 + ww * 7) * CDIM;
  #pragma unroll
  for (int mt = 0; mt < 4; ++mt) {
    bf16x8 ao[4];
    #pragma unroll
    for (int kt = 0; kt < 4; ++kt)
      ao[kt] = *(const bf16x8*)(xo_ + rb[mt] + kt * 64 + lg * 16);
    f32x4 c0; c0[0]=0.f; c0[1]=0.f; c0[2]=0.f; c0[3]=0.f;
    #pragma unroll
    for (int kt = 0; kt < 4; ++kt) c0 = mfma32(ao[kt], bp[kt], c0);
    #pragma unroll
    for (int i = 0; i < 4; ++i) {
      const int r = mt * 16 + lg * 4 + i;
      if (r < NTOK) {
        float* po = outw + ((r / 7) * 56 + (r % 7)) * CDIM + chw;
        po[l15] = c0[i] + pb;
      }
    }
  }
}

extern "C" void kernel_launch(void* const* d_in, const int* in_sizes, int n_in,
                              void* d_out, int out_size, void* d_ws, size_t ws_size,
                              hipStream_t stream) {
  const float* x          = (const float*)d_in[0];
  const float* qkv_w      = (const float*)d_in[1];
  const float* qkv_b      = (const float*)d_in[2];
  const float* proj_w     = (const float*)d_in[3];
  const float* proj_b     = (const float*)d_in[4];
  const float* bias_table = (const float*)d_in[5];

  __bf16* qkvT  = (__bf16*)d_ws;
  __bf16* projT = qkvT + C3 * CDIM;
  float*  blut  = (float*)((char*)d_ws + 131072);
  float*  out   = (float*)d_out;

  hipLaunchKernelGGL(prep_kernel, dim3(320), dim3(256), 0, stream,
                     qkv_w, proj_w, bias_table, qkvT, projT, blut);
  hipLaunchKernelGGL(attn_kernel, dim3(4096), dim3(512), 0, stream,
                     x, qkv_b, proj_b, (const char*)d_ws, out);
}